// Round 9
// baseline (889.358 us; speedup 1.0000x reference)
//
#include <hip/hip_runtime.h>

// SemaEmb GIN network — round 9: channel-phase-split gather (half-row passes,
// 4-phase dispatch order) to shrink the L2 working set. Rest identical to round 8.
// N=100000, E=1600000, EMB=128, L=3, P=4.

typedef unsigned int  uint;
typedef unsigned short ushort;
typedef float  f32x4  __attribute__((ext_vector_type(4)));
typedef short  bf16x8 __attribute__((ext_vector_type(8)));

#define ABITS 9          // 512 nodes per bin
#define CAPB  12288      // entries per bin segment
#define CHUNK 2048       // edges per binpass block

__device__ __forceinline__ float lrelu(float x) { return x > 0.0f ? x : 0.01f * x; }
__device__ __forceinline__ ushort f2b(float x) {
    uint u = __float_as_uint(x);
    return (ushort)((u + 0x7fffu + ((u >> 16) & 1u)) >> 16);
}
__device__ __forceinline__ float lof(uint u) { return __uint_as_float(u << 16); }
__device__ __forceinline__ float hif(uint u) { return __uint_as_float(u & 0xffff0000u); }

// ---------------- fp32 folded tables: A[t*64+v][j] = emb_t[v] @ W1 block t ----------------
__global__ void tables_kernel(const float* __restrict__ opT, const float* __restrict__ parT,
                              const float* __restrict__ W1, float* __restrict__ A)
{
    int b = blockIdx.x;            // 0..319 : t*64+v
    int t = b >> 6, v = b & 63, j = threadIdx.x;
    const float* emb = (t == 0 ? opT : parT) + v * 128;
    const float* w = W1 + (size_t)t * 128 * 128;
    float acc = 0.f;
    for (int k = 0; k < 128; ++k) acc += emb[k] * w[k * 128 + j];
    A[(size_t)b * 128 + j] = acc;
}

// ---------------- bf16 transposed + pre-swizzled weight images ----------------
// Image byte layout: c*256 + ((k>>3)^(c&7))*16 + (k&7)*2   (row = output channel c)
__global__ void prep_w(const float* __restrict__ convw, const float* __restrict__ ow2,
                       const float* __restrict__ cw, ushort* __restrict__ Wt)
{
    int t = blockIdx.x * 256 + threadIdx.x;     // 6 images * 16384
    int img = t >> 14, idx = t & 16383;
    int k = idx >> 7, c = idx & 127;
    const float* src;
    if (img < 3)      src = convw + img * 16384;
    else if (img == 3) src = ow2;
    else              src = cw + (img - 4) * 16384;
    float v = src[k * 128 + c];
    int byteoff = (img << 15) + (c << 8) + ((((k >> 3) ^ (c & 7)) << 4)) + ((k & 7) << 1);
    Wt[byteoff >> 1] = f2b(v);
}

// ---------------- CSR build pass A: bin edges by key>>ABITS (both directions) ----------------
__global__ __launch_bounds__(256) void binpass_kernel(
    const int* __restrict__ esrc, const int* __restrict__ edst, int E, int nb,
    int* __restrict__ gcur, uint2* __restrict__ binbuf)
{
    __shared__ int hist[448];
    __shared__ int lstart[448];
    __shared__ int gbase[448];
    __shared__ int lcur[448];
    __shared__ int gsum[8];
    __shared__ uint sKey[CHUNK * 2];
    __shared__ uint sPay[CHUNK * 2];
    __shared__ ushort sBin[CHUNK * 2];
    int tid = threadIdx.x, lane = tid & 63;
    int nb2 = nb * 2;

    for (int chunk = blockIdx.x; (size_t)chunk * CHUNK < (size_t)E; chunk += gridDim.x) {
        int base = chunk * CHUNK;
        int cnt = min(CHUNK, E - base);
        for (int i = tid; i < 448; i += 256) hist[i] = 0;
        __syncthreads();
        int s[8], d[8];
        #pragma unroll
        for (int i = 0; i < 8; ++i) {
            int idx = i * 256 + tid;
            if (idx < cnt) {
                s[i] = esrc[base + idx];
                d[i] = edst[base + idx];
                atomicAdd(&hist[d[i] >> ABITS], 1);
                atomicAdd(&hist[nb + (s[i] >> ABITS)], 1);
            } else s[i] = -1;
        }
        __syncthreads();
        #pragma unroll
        for (int k = 0; k < 2; ++k) {
            int idx = k * 256 + tid;
            int v = (idx < 448) ? hist[idx] : 0;
            int p = v;
            #pragma unroll
            for (int sh = 1; sh < 64; sh <<= 1) { int t = __shfl_up(p, sh, 64); if (lane >= sh) p += t; }
            if (idx < 448) {
                lstart[idx] = p - v;
                if (lane == 63) gsum[idx >> 6] = p;
            }
        }
        __syncthreads();
        if (tid == 0) { int run = 0; for (int g = 0; g < 7; ++g) { int t = gsum[g]; gsum[g] = run; run += t; } }
        __syncthreads();
        #pragma unroll
        for (int k = 0; k < 2; ++k) {
            int idx = k * 256 + tid;
            if (idx < 448) lstart[idx] += gsum[idx >> 6];
        }
        __syncthreads();
        for (int i = tid; i < nb2; i += 256) {
            int h = hist[i];
            gbase[i] = h ? atomicAdd(&gcur[i], h) : 0;
            lcur[i] = lstart[i];
        }
        __syncthreads();
        #pragma unroll
        for (int i = 0; i < 8; ++i) {
            if (s[i] >= 0) {
                int bf = d[i] >> ABITS;
                int p = atomicAdd(&lcur[bf], 1);
                sKey[p] = (uint)d[i]; sPay[p] = (uint)s[i]; sBin[p] = (ushort)bf;
                int bi = nb + (s[i] >> ABITS);
                int q = atomicAdd(&lcur[bi], 1);
                sKey[q] = (uint)s[i]; sPay[q] = (uint)d[i]; sBin[q] = (ushort)bi;
            }
        }
        __syncthreads();
        int total = 2 * cnt;
        for (int p = tid; p < total; p += 256) {
            int b = sBin[p];
            int pos = gbase[b] + (p - lstart[b]);
            if (pos < CAPB) binbuf[(size_t)b * CAPB + pos] = make_uint2(sKey[p], sPay[p]);
        }
        __syncthreads();
    }
}

// ---------------- CSR build pass B: per-bin CSR + off/cnt; csr entries = BYTE offsets ------
__global__ __launch_bounds__(256) void csrpass_kernel(
    const uint2* __restrict__ binbuf, const int* __restrict__ gcur, int nb, int N,
    int* __restrict__ csr_f, int* __restrict__ off_f, int* __restrict__ cnt_f,
    int* __restrict__ csr_i, int* __restrict__ off_i, int* __restrict__ cnt_i)
{
    __shared__ int hist[512];
    __shared__ int loff[512];
    __shared__ int cur[512];
    __shared__ int gsum[8];
    int b = blockIdx.x;
    int dir = (b >= nb) ? 1 : 0;
    int binLocal = dir ? b - nb : b;
    int node0 = binLocal << ABITS;
    int nn = min(512, N - node0);
    int tid = threadIdx.x, lane = tid & 63;
    int total = min(gcur[b], CAPB);
    const uint2* seg = binbuf + (size_t)b * CAPB;
    int* csr = dir ? csr_i : csr_f;
    int* off = dir ? off_i : off_f;
    int* cnt = dir ? cnt_i : cnt_f;

    for (int i = tid; i < 512; i += 256) hist[i] = 0;
    __syncthreads();
    for (int e = tid; e < total; e += 256) {
        uint2 kp = seg[e];
        atomicAdd(&hist[kp.x - (uint)node0], 1);
    }
    __syncthreads();
    #pragma unroll
    for (int k = 0; k < 2; ++k) {
        int idx = k * 256 + tid;
        int v = hist[idx];
        int p = v;
        #pragma unroll
        for (int sh = 1; sh < 64; sh <<= 1) { int t = __shfl_up(p, sh, 64); if (lane >= sh) p += t; }
        loff[idx] = p - v;
        if (lane == 63) gsum[idx >> 6] = p;
    }
    __syncthreads();
    if (tid == 0) { int run = 0; for (int g = 0; g < 8; ++g) { int t = gsum[g]; gsum[g] = run; run += t; } }
    __syncthreads();
    #pragma unroll
    for (int k = 0; k < 2; ++k) {
        int idx = k * 256 + tid;
        loff[idx] += gsum[idx >> 6];
    }
    __syncthreads();
    int csrBase = binLocal * CAPB;
    for (int i = tid; i < 512; i += 256) {
        cur[i] = loff[i];
        if (i < nn) { off[node0 + i] = csrBase + loff[i]; cnt[node0 + i] = hist[i]; }
    }
    __syncthreads();
    int* csrSeg = csr + csrBase;
    for (int e = tid; e < total; e += 256) {
        uint2 kp = seg[e];
        int p = atomicAdd(&cur[kp.x - (uint)node0], 1);
        csrSeg[p] = (int)(kp.y << 8);        // neighbor row BYTE offset (node*256)
    }
}

// ---------------- aggregation, channel-phase split: msg = self + mean(nbrs), bf16 ----------
// 4 dispatch phases (blockIdx order): h0-fwd, h0-inv, h1-fwd, h1-inv.
// Per phase a wave gathers one node's HALF-rows (128 B): 32 lanes x uint = 1 half-row,
// so each load instruction covers 2 neighbors. Working set/phase = 12.8 MB.
__global__ __launch_bounds__(256, 8) void agg3_kernel(
    const ushort* __restrict__ Sf, const ushort* __restrict__ Si,
    const int* __restrict__ csr_f, const int* __restrict__ off_f, const int* __restrict__ cnt_f,
    const int* __restrict__ csr_i, const int* __restrict__ off_i, const int* __restrict__ cnt_i,
    ushort* __restrict__ msgf, ushort* __restrict__ msgi, int N)
{
    int gw = (blockIdx.x * 256 + threadIdx.x) >> 6;   // wave id in [0, 4N)
    int lane = threadIdx.x & 63;
    int g = gw, half = 0, dir = 0;
    if (g >= 2 * N) { half = 1; g -= 2 * N; }
    if (g >= N)     { dir = 1;  g -= N; }
    if (g >= N) return;

    const char* Sp = (const char*)(dir ? Si : Sf);
    const int* csr = dir ? csr_i : csr_f;
    int off = (dir ? off_i : off_f)[g];
    int deg = (dir ? cnt_i : cnt_f)[g];
    int hw = lane >> 5;                          // which neighbor of the pair
    int lb = ((lane & 31) << 2) + (half << 7);   // byte offset within a row (half-selected)

    float a0 = 0.f, a1 = 0.f;
    int d = 0;
    for (; d + 8 <= deg; d += 8) {               // 8 neighbors / iter, 4 loads / lane
        int b0 = csr[off + d + 0 + hw];
        int b1 = csr[off + d + 2 + hw];
        int b2 = csr[off + d + 4 + hw];
        int b3 = csr[off + d + 6 + hw];
        uint v0 = *(const uint*)(Sp + (uint)(b0 + lb));
        uint v1 = *(const uint*)(Sp + (uint)(b1 + lb));
        uint v2 = *(const uint*)(Sp + (uint)(b2 + lb));
        uint v3 = *(const uint*)(Sp + (uint)(b3 + lb));
        a0 += (lof(v0) + lof(v1)) + (lof(v2) + lof(v3));
        a1 += (hif(v0) + hif(v1)) + (hif(v2) + hif(v3));
    }
    for (; d + 2 <= deg; d += 2) {               // 2 neighbors / iter, 1 load
        int b = csr[off + d + hw];
        uint v = *(const uint*)(Sp + (uint)(b + lb));
        a0 += lof(v); a1 += hif(v);
    }
    if (d < deg && hw == 0) {                    // odd tail: half-wave 0 only
        int b = csr[off + d];
        uint v = *(const uint*)(Sp + (uint)(b + lb));
        a0 += lof(v); a1 += hif(v);
    }
    a0 += __shfl_xor(a0, 32);
    a1 += __shfl_xor(a1, 32);
    float invd = 1.0f / fmaxf((float)deg, 1.0f);
    uint self = *(const uint*)(Sp + ((size_t)g << 8) + lb);
    a0 = lof(self) + a0 * invd;
    a1 = hif(self) + a1 * invd;
    if (hw == 0) {
        *(uint*)((char*)(dir ? msgi : msgf) + ((size_t)g << 8) + lb)
            = (uint)f2b(a0) | ((uint)f2b(a1) << 16);
    }
}

// ---------------- MFMA helpers ----------------
__device__ __forceinline__ void stage_w(const ushort* __restrict__ img, ushort* ldsW, int tid)
{
    const uint4* s = (const uint4*)img;
    uint4* d = (uint4*)ldsW;
    #pragma unroll
    for (int i = 0; i < 4; ++i) d[tid + (i << 9)] = s[tid + (i << 9)];
}

// ---------------- GIN layer GEMM from msg (both dirs): lrelu(msg @ W + b) ----------------
__global__ __launch_bounds__(512, 8) void gemm2_kernel(
    const ushort* __restrict__ msgf, const ushort* __restrict__ msgi,
    ushort* __restrict__ Sf_out, ushort* __restrict__ Si_out,
    const ushort* __restrict__ Wimg, const float* __restrict__ bias,
    float* __restrict__ colsum, int N)
{
    __shared__ __align__(16) ushort ldsW[16384];
    __shared__ float ldsCS[128];
    int tid = threadIdx.x, lane = tid & 63, w = tid >> 6;
    bool fwd = (blockIdx.x & 1) == 0;
    int node0 = (blockIdx.x >> 1) << 7;
    const ushort* msg = fwd ? msgf : msgi;
    ushort* Sout = fwd ? Sf_out : Si_out;

    stage_w(Wimg, ldsW, tid);
    if (fwd && tid < 128) ldsCS[tid] = 0.f;
    __syncthreads();

    int l15 = lane & 15, lg = lane >> 4;
    int node = node0 + (w << 4) + l15;
    int gr = min(node, N - 1);
    const char* Bb = (const char*)msg + ((size_t)gr << 8);

    f32x4 acc[8];
    #pragma unroll
    for (int i = 0; i < 8; ++i) acc[i] = f32x4{0.f, 0.f, 0.f, 0.f};
    #pragma unroll
    for (int kk = 0; kk < 4; ++kk) {
        bf16x8 bfr = *(const bf16x8*)(Bb + (((kk << 2) + lg) << 4));
        #pragma unroll
        for (int ct = 0; ct < 8; ++ct) {
            int c = (ct << 4) + l15;
            const char* Ab = (const char*)ldsW + c * 256;
            bf16x8 af = *(const bf16x8*)(Ab + ((((kk << 2) + lg) << 4) ^ ((c & 7) << 4)));
            acc[ct] = __builtin_amdgcn_mfma_f32_16x16x32_bf16(af, bfr, acc[ct], 0, 0, 0);
        }
    }

    bool valid = node < N;
    #pragma unroll
    for (int ct = 0; ct < 8; ++ct) {
        int ch0 = (ct << 4) + (lg << 2);
        float4 bb = *(const float4*)(bias + ch0);
        float o0 = lrelu(acc[ct][0] + bb.x);
        float o1 = lrelu(acc[ct][1] + bb.y);
        float o2 = lrelu(acc[ct][2] + bb.z);
        float o3 = lrelu(acc[ct][3] + bb.w);
        if (valid) {
            uint2 pk;
            pk.x = (uint)f2b(o0) | ((uint)f2b(o1) << 16);
            pk.y = (uint)f2b(o2) | ((uint)f2b(o3) << 16);
            *(uint2*)((char*)Sout + ((size_t)node << 8) + (ch0 << 1)) = pk;
        }
        if (fwd) {
            float c0 = valid ? o0 : 0.f, c1 = valid ? o1 : 0.f;
            float c2 = valid ? o2 : 0.f, c3 = valid ? o3 : 0.f;
            #pragma unroll
            for (int m = 1; m < 16; m <<= 1) {
                c0 += __shfl_xor(c0, m);
                c1 += __shfl_xor(c1, m);
                c2 += __shfl_xor(c2, m);
                c3 += __shfl_xor(c3, m);
            }
            if (l15 == 0) {
                atomicAdd(&ldsCS[ch0 + 0], c0);
                atomicAdd(&ldsCS[ch0 + 1], c1);
                atomicAdd(&ldsCS[ch0 + 2], c2);
                atomicAdd(&ldsCS[ch0 + 3], c3);
            }
        }
    }
    if (fwd) {
        __syncthreads();
        if (tid < 128) atomicAdd(&colsum[tid], ldsCS[tid]);
    }
}

// ---------------- op embedding MLP (tables -> lrelu -> @W2+b2), bf16 out ----------------
__global__ __launch_bounds__(512, 4) void opemb_fused(
    const int* __restrict__ ops, const int* __restrict__ params,
    const float* __restrict__ Atab, const float* __restrict__ b1,
    const ushort* __restrict__ W2img, const float* __restrict__ b2,
    ushort* __restrict__ S0, int N)
{
    __shared__ __align__(16) ushort ldsW[16384];
    __shared__ __align__(16) ushort ldsA[16384];
    int tid = threadIdx.x, lane = tid & 63, w = tid >> 6;
    int node0 = blockIdx.x << 7;

    stage_w(W2img, ldsW, tid);

    int r = tid >> 2, sub = tid & 3;      // 4 threads/row, 32 cols each
    int g = node0 + r;
    float4 acc4[8];
    if (g < N) {
        int op = ops[g];
        const float4* T = (const float4*)(Atab + ((size_t)op << 7) + (sub << 5));
        #pragma unroll
        for (int q = 0; q < 8; ++q) acc4[q] = T[q];
        #pragma unroll
        for (int p = 0; p < 4; ++p) {
            int pv = params[(g << 2) + p];
            const float4* Tp = (const float4*)(Atab + ((size_t)((p + 1) * 64 + pv) << 7) + (sub << 5));
            #pragma unroll
            for (int q = 0; q < 8; ++q) {
                float4 u = Tp[q];
                acc4[q].x += u.x; acc4[q].y += u.y; acc4[q].z += u.z; acc4[q].w += u.w;
            }
        }
        const float4* Bv = (const float4*)(b1 + (sub << 5));
        #pragma unroll
        for (int q = 0; q < 8; ++q) {
            float4 bb = Bv[q];
            acc4[q].x = lrelu(acc4[q].x + bb.x);
            acc4[q].y = lrelu(acc4[q].y + bb.y);
            acc4[q].z = lrelu(acc4[q].z + bb.z);
            acc4[q].w = lrelu(acc4[q].w + bb.w);
        }
    } else {
        #pragma unroll
        for (int q = 0; q < 8; ++q) acc4[q] = make_float4(0.f, 0.f, 0.f, 0.f);
    }
    int akey = r & 7;
    #pragma unroll
    for (int q2 = 0; q2 < 4; ++q2) {
        int ch = (sub << 2) + q2;
        float4 a = acc4[q2 * 2], b = acc4[q2 * 2 + 1];
        uint4 pk;
        pk.x = (uint)f2b(a.x) | ((uint)f2b(a.y) << 16);
        pk.y = (uint)f2b(a.z) | ((uint)f2b(a.w) << 16);
        pk.z = (uint)f2b(b.x) | ((uint)f2b(b.y) << 16);
        pk.w = (uint)f2b(b.z) | ((uint)f2b(b.w) << 16);
        *(uint4*)((char*)ldsA + r * 256 + ((ch ^ akey) << 4)) = pk;
    }
    __syncthreads();

    // Swapped-operand MFMA: A = W^T (ldsW), B = h^T (ldsA)
    int l15 = lane & 15, lg = lane >> 4;
    int node = node0 + (w << 4) + l15;
    int brow = (w << 4) + l15;
    const char* Bb = (const char*)ldsA + brow * 256;
    int bkey = (brow & 7) << 4;
    f32x4 acc[8];
    #pragma unroll
    for (int i = 0; i < 8; ++i) acc[i] = f32x4{0.f, 0.f, 0.f, 0.f};
    #pragma unroll
    for (int kk = 0; kk < 4; ++kk) {
        bf16x8 bfr = *(const bf16x8*)(Bb + ((((kk << 2) + lg) << 4) ^ bkey));
        #pragma unroll
        for (int ct = 0; ct < 8; ++ct) {
            int c = (ct << 4) + l15;
            const char* Ab = (const char*)ldsW + c * 256;
            bf16x8 af = *(const bf16x8*)(Ab + ((((kk << 2) + lg) << 4) ^ ((c & 7) << 4)));
            acc[ct] = __builtin_amdgcn_mfma_f32_16x16x32_bf16(af, bfr, acc[ct], 0, 0, 0);
        }
    }
    if (node < N) {
        #pragma unroll
        for (int ct = 0; ct < 8; ++ct) {
            int ch0 = (ct << 4) + (lg << 2);
            float4 bb = *(const float4*)(b2 + ch0);
            uint2 pk;                                   // no lrelu on layer 2
            pk.x = (uint)f2b(acc[ct][0] + bb.x) | ((uint)f2b(acc[ct][1] + bb.y) << 16);
            pk.y = (uint)f2b(acc[ct][2] + bb.z) | ((uint)f2b(acc[ct][3] + bb.w) << 16);
            *(uint2*)((char*)S0 + ((size_t)node << 8) + (ch0 << 1)) = pk;
        }
    }
}

// ---------------- graph-level heads (parallel, 512 threads, runs as one out2 block) --------
__device__ __forceinline__ void final_body(
    float* lds, const float* __restrict__ convsum,
    const float* __restrict__ mw1, const float* __restrict__ mb1,
    const float* __restrict__ mw2, const float* __restrict__ mb2,
    const float* __restrict__ iw1, const float* __restrict__ ib1,
    const float* __restrict__ iw2, const float* __restrict__ ib2,
    const float* __restrict__ cw, const float* __restrict__ cb,
    float* __restrict__ out1)
{
    float* x  = lds;          // 384
    float* pa = lds + 384;    // 512
    float* pb = lds + 896;    // 512
    float* t1 = lds + 1408;   // 128
    float* t2 = lds + 1536;   // 128
    int tid = threadIdx.x, j = tid & 127, s = tid >> 7;   // 4 k-slices
    if (tid < 384) x[tid] = convsum[tid];
    __syncthreads();
    float a = 0.f, c = 0.f;
    for (int k = s * 96; k < s * 96 + 96; ++k) {
        a += x[k] * mw1[k * 128 + j];
        c += x[256 + (k & 127)] * iw1[k * 128 + j];
    }
    pa[tid] = a; pb[tid] = c;
    __syncthreads();
    if (s == 0) {
        t1[j] = lrelu(pa[j] + pa[128 + j] + pa[256 + j] + pa[384 + j] + mb1[j]);
        t2[j] = lrelu(pb[j] + pb[128 + j] + pb[256 + j] + pb[384 + j] + ib1[j]);
    }
    __syncthreads();
    float b = 0.f, d = 0.f;
    for (int k = s * 32; k < s * 32 + 32; ++k) {
        b += t1[k] * mw2[k * 128 + j];
        d += t2[k] * iw2[k * 128 + j];
    }
    pa[tid] = b; pb[tid] = d;
    __syncthreads();
    if (s == 0) {
        t1[j] = pa[j] + pa[128 + j] + pa[256 + j] + pa[384 + j] + mb2[j];   // g1
        t2[j] = pb[j] + pb[128 + j] + pb[256 + j] + pb[384 + j] + ib2[j];   // g2
    }
    __syncthreads();
    float e = 0.f;
    for (int k = s * 32; k < s * 32 + 32; ++k)
        e += t1[k] * cw[k * 128 + j] + t2[k] * cw[(128 + k) * 128 + j];
    pa[tid] = e;
    __syncthreads();
    if (s == 0) out1[j] = pa[j] + pa[128 + j] + pa[256 + j] + pa[384 + j] + cb[j];
}

// ---------------- out2 = [Sf | Si] @ comb_w + comb_b (fp32 out) + final block --------------
__global__ __launch_bounds__(512, 4) void out2_fused(
    const ushort* __restrict__ Sf, const ushort* __restrict__ Si,
    const ushort* __restrict__ CWimg, const float* __restrict__ cb,
    float* __restrict__ out, int gemmBlocks, int N,
    const float* __restrict__ convsum,
    const float* __restrict__ mw1, const float* __restrict__ mb1,
    const float* __restrict__ mw2, const float* __restrict__ mb2,
    const float* __restrict__ iw1, const float* __restrict__ ib1,
    const float* __restrict__ iw2, const float* __restrict__ ib2,
    const float* __restrict__ cw, float* __restrict__ out1)
{
    __shared__ __align__(16) ushort ldsW[16384];
    int tid = threadIdx.x, lane = tid & 63, w = tid >> 6;
    if ((int)blockIdx.x >= gemmBlocks) {
        final_body((float*)ldsW, convsum, mw1, mb1, mw2, mb2,
                   iw1, ib1, iw2, ib2, cw, cb, out1);
        return;
    }
    int node0 = blockIdx.x << 7;
    int l15 = lane & 15, lg = lane >> 4;
    int node = node0 + (w << 4) + l15;
    int gr = min(node, N - 1);
    f32x4 acc[8];
    #pragma unroll
    for (int i = 0; i < 8; ++i) acc[i] = f32x4{0.f, 0.f, 0.f, 0.f};
    #pragma unroll
    for (int pass = 0; pass < 2; ++pass) {
        if (pass) __syncthreads();
        stage_w(CWimg + (pass << 14), ldsW, tid);
        __syncthreads();
        const char* Bb = (const char*)(pass ? Si : Sf) + ((size_t)gr << 8);
        #pragma unroll
        for (int kk = 0; kk < 4; ++kk) {
            bf16x8 bfr = *(const bf16x8*)(Bb + (((kk << 2) + lg) << 4));
            #pragma unroll
            for (int ct = 0; ct < 8; ++ct) {
                int c = (ct << 4) + l15;
                const char* Ab = (const char*)ldsW + c * 256;
                bf16x8 af = *(const bf16x8*)(Ab + ((((kk << 2) + lg) << 4) ^ ((c & 7) << 4)));
                acc[ct] = __builtin_amdgcn_mfma_f32_16x16x32_bf16(af, bfr, acc[ct], 0, 0, 0);
            }
        }
    }
    if (node < N) {
        #pragma unroll
        for (int ct = 0; ct < 8; ++ct) {
            int ch0 = (ct << 4) + (lg << 2);
            float4 bb = *(const float4*)(cb + ch0);
            float4 o;
            o.x = acc[ct][0] + bb.x;
            o.y = acc[ct][1] + bb.y;
            o.z = acc[ct][2] + bb.z;
            o.w = acc[ct][3] + bb.w;
            *(float4*)(out + (size_t)node * 128 + ch0) = o;
        }
    }
}

extern "C" void kernel_launch(void* const* d_in, const int* in_sizes, int n_in,
                              void* d_out, int out_size, void* d_ws, size_t ws_size,
                              hipStream_t stream)
{
    (void)n_in; (void)out_size; (void)ws_size;
    const int*   ops    = (const int*)d_in[0];
    const int*   params = (const int*)d_in[1];
    const int*   esrc   = (const int*)d_in[2];
    const int*   edst   = (const int*)d_in[3];
    const float* opT    = (const float*)d_in[4];
    const float* parT   = (const float*)d_in[5];
    const float* ow1    = (const float*)d_in[6];
    const float* ob1    = (const float*)d_in[7];
    const float* ow2    = (const float*)d_in[8];
    const float* ob2    = (const float*)d_in[9];
    const float* convw  = (const float*)d_in[10];
    const float* convb  = (const float*)d_in[11];
    const float* mw1    = (const float*)d_in[12];
    const float* mb1    = (const float*)d_in[13];
    const float* mw2    = (const float*)d_in[14];
    const float* mb2    = (const float*)d_in[15];
    const float* iw1    = (const float*)d_in[16];
    const float* ib1    = (const float*)d_in[17];
    const float* iw2    = (const float*)d_in[18];
    const float* ib2    = (const float*)d_in[19];
    const float* cw     = (const float*)d_in[20];
    const float* cb     = (const float*)d_in[21];

    const int N = in_sizes[0];      // 100000
    const int E = in_sizes[2];      // 1600000
    const int nb = (N + 511) >> ABITS;   // 196 bins per direction
    const size_t NP = (size_t)N * 128;

    // workspace layout (~162 MB)
    ushort* S0   = (ushort*)d_ws;                    // [N][128] bf16
    ushort* S1   = S0 + NP;
    ushort* S2   = S1 + NP;
    ushort* S3   = S2 + NP;
    ushort* Wt   = S3 + NP;                          // 6 * 16384 bf16 images
    float*  Atab = (float*)(Wt + 6 * 16384);         // 320*128 fp32
    float*  convsum = Atab + 320 * 128;              // 384 used, 512 reserved
    int*    gcur = (int*)(convsum + 512);            // 2*nb used, 512 reserved
    uint2*  binbuf = (uint2*)(gcur + 512);           // 2*nb*CAPB entries
    int*    csr_f = (int*)(binbuf + (size_t)2 * nb * CAPB);   // nb*CAPB
    int*    csr_i = csr_f + (size_t)nb * CAPB;
    int*    off_f = csr_i + (size_t)nb * CAPB;       // N each
    int*    cnt_f = off_f + N;
    int*    off_i = cnt_f + N;
    int*    cnt_i = off_i + N;

    float* out1 = (float*)d_out;
    float* out2 = out1 + 128;
    // msg buffers live in the (dead until the end) out2 region
    ushort* MSGF = (ushort*)out2;
    ushort* MSGI = MSGF + NP;

    hipMemsetAsync(convsum, 0, sizeof(float) * 1024, stream);   // convsum + gcur

    tables_kernel<<<320, 128, 0, stream>>>(opT, parT, ow1, Atab);
    prep_w<<<384, 256, 0, stream>>>(convw, ow2, cw, Wt);
    binpass_kernel<<<(E + CHUNK - 1) / CHUNK, 256, 0, stream>>>(esrc, edst, E, nb, gcur, binbuf);
    csrpass_kernel<<<2 * nb, 256, 0, stream>>>(binbuf, gcur, nb, N,
                                               csr_f, off_f, cnt_f, csr_i, off_i, cnt_i);

    const int grid = (N + 127) / 128;          // 782
    opemb_fused<<<grid, 512, 0, stream>>>(ops, params, Atab, ob1, Wt + 3 * 16384, ob2, S0, N);

    const int aggGrid = N;                     // 4N waves / 4 waves-per-block
    // layer 0: fwd S0->S1 (colsum), inv S0->S3   [layer-0 dedup: both read S0]
    agg3_kernel<<<aggGrid, 256, 0, stream>>>(S0, S0, csr_f, off_f, cnt_f, csr_i, off_i, cnt_i, MSGF, MSGI, N);
    gemm2_kernel<<<2 * grid, 512, 0, stream>>>(MSGF, MSGI, S1, S3, Wt,             convb,       convsum,       N);
    // layer 1: fwd S1->S0, inv S3->S2
    agg3_kernel<<<aggGrid, 256, 0, stream>>>(S1, S3, csr_f, off_f, cnt_f, csr_i, off_i, cnt_i, MSGF, MSGI, N);
    gemm2_kernel<<<2 * grid, 512, 0, stream>>>(MSGF, MSGI, S0, S2, Wt + 16384,     convb + 128, convsum + 128, N);
    // layer 2: fwd S0->S1, inv S2->S3
    agg3_kernel<<<aggGrid, 256, 0, stream>>>(S0, S2, csr_f, off_f, cnt_f, csr_i, off_i, cnt_i, MSGF, MSGI, N);
    gemm2_kernel<<<2 * grid, 512, 0, stream>>>(MSGF, MSGI, S1, S3, Wt + 2 * 16384, convb + 256, convsum + 256, N);

    // out2 (782 gemm blocks) + final head (1 extra block, overlapped)
    out2_fused<<<grid + 1, 512, 0, stream>>>(S1, S3, Wt + 4 * 16384, cb, out2, grid, N,
                                             convsum, mw1, mb1, mw2, mb2,
                                             iw1, ib1, iw2, ib2, cw, out1);
}

// Round 10
// 655.298 us; speedup vs baseline: 1.3572x; 1.3572x over previous
//
#include <hip/hip_runtime.h>

// SemaEmb GIN network — round 10: round-8 agg restored (best measured, 4 gather
// variants refuted), kernel-count reduction: buildprep = binpass+tables+prep_w,
// mid = csrpass(512t)+opemb. N=100000, E=1600000, EMB=128, L=3, P=4.

typedef unsigned int  uint;
typedef unsigned short ushort;
typedef float  f32x4  __attribute__((ext_vector_type(4)));
typedef short  bf16x8 __attribute__((ext_vector_type(8)));

#define ABITS 9          // 512 nodes per bin
#define CAPB  12288      // entries per bin segment
#define CHUNK 2048       // edges per binpass block

__device__ __forceinline__ float lrelu(float x) { return x > 0.0f ? x : 0.01f * x; }
__device__ __forceinline__ ushort f2b(float x) {
    uint u = __float_as_uint(x);
    return (ushort)((u + 0x7fffu + ((u >> 16) & 1u)) >> 16);
}
__device__ __forceinline__ float lof(uint u) { return __uint_as_float(u << 16); }
__device__ __forceinline__ float hif(uint u) { return __uint_as_float(u & 0xffff0000u); }

// ============ buildprep: [0,nChunks) binpass | [nChunks,+160) tables | rest prep_w =========
__global__ __launch_bounds__(256) void buildprep_kernel(
    const int* __restrict__ esrc, const int* __restrict__ edst, int E, int nb, int nChunks,
    int* __restrict__ gcur, uint2* __restrict__ binbuf,
    const float* __restrict__ opT, const float* __restrict__ parT,
    const float* __restrict__ W1, float* __restrict__ Atab,
    const float* __restrict__ convw, const float* __restrict__ ow2,
    const float* __restrict__ cw, ushort* __restrict__ Wt)
{
    __shared__ int hist[448];
    __shared__ int lstart[448];
    __shared__ int gbase[448];
    __shared__ int lcur[448];
    __shared__ int gsum[8];
    __shared__ uint sKey[CHUNK * 2];
    __shared__ uint sPay[CHUNK * 2];
    __shared__ ushort sBin[CHUNK * 2];
    int tid = threadIdx.x, lane = tid & 63;

    if ((int)blockIdx.x >= nChunks) {
        int rb = (int)blockIdx.x - nChunks;
        if (rb < 160) {
            // tables: Atab[b][j] = emb @ W1 block; 2 b-values per block
            int b = (rb << 1) | (tid >> 7);
            int t = b >> 6, v = b & 63, j = tid & 127;
            const float* emb = (t == 0 ? opT : parT) + v * 128;
            const float* w = W1 + (size_t)t * 128 * 128;
            float acc = 0.f;
            for (int k = 0; k < 128; ++k) acc += emb[k] * w[k * 128 + j];
            Atab[(size_t)b * 128 + j] = acc;
        } else {
            // prep_w: bf16 transposed + swizzled weight images
            int t = (rb - 160) * 256 + tid;
            int img = t >> 14, idx = t & 16383;
            int k = idx >> 7, c = idx & 127;
            const float* src;
            if (img < 3)       src = convw + img * 16384;
            else if (img == 3) src = ow2;
            else               src = cw + (img - 4) * 16384;
            float v = src[k * 128 + c];
            int byteoff = (img << 15) + (c << 8) + ((((k >> 3) ^ (c & 7)) << 4)) + ((k & 7) << 1);
            Wt[byteoff >> 1] = f2b(v);
        }
        return;
    }

    // binpass: one chunk per block
    int nb2 = nb * 2;
    int base = (int)blockIdx.x * CHUNK;
    int cnt = min(CHUNK, E - base);
    for (int i = tid; i < 448; i += 256) hist[i] = 0;
    __syncthreads();
    int s[8], d[8];
    #pragma unroll
    for (int i = 0; i < 8; ++i) {
        int idx = i * 256 + tid;
        if (idx < cnt) {
            s[i] = esrc[base + idx];
            d[i] = edst[base + idx];
            atomicAdd(&hist[d[i] >> ABITS], 1);
            atomicAdd(&hist[nb + (s[i] >> ABITS)], 1);
        } else s[i] = -1;
    }
    __syncthreads();
    #pragma unroll
    for (int k = 0; k < 2; ++k) {
        int idx = k * 256 + tid;
        int v = (idx < 448) ? hist[idx] : 0;
        int p = v;
        #pragma unroll
        for (int sh = 1; sh < 64; sh <<= 1) { int t = __shfl_up(p, sh, 64); if (lane >= sh) p += t; }
        if (idx < 448) {
            lstart[idx] = p - v;
            if (lane == 63) gsum[idx >> 6] = p;
        }
    }
    __syncthreads();
    if (tid == 0) { int run = 0; for (int g = 0; g < 7; ++g) { int t = gsum[g]; gsum[g] = run; run += t; } }
    __syncthreads();
    #pragma unroll
    for (int k = 0; k < 2; ++k) {
        int idx = k * 256 + tid;
        if (idx < 448) lstart[idx] += gsum[idx >> 6];
    }
    __syncthreads();
    for (int i = tid; i < nb2; i += 256) {
        int h = hist[i];
        gbase[i] = h ? atomicAdd(&gcur[i], h) : 0;
        lcur[i] = lstart[i];
    }
    __syncthreads();
    #pragma unroll
    for (int i = 0; i < 8; ++i) {
        if (s[i] >= 0) {
            int bf = d[i] >> ABITS;
            int p = atomicAdd(&lcur[bf], 1);
            sKey[p] = (uint)d[i]; sPay[p] = (uint)s[i]; sBin[p] = (ushort)bf;
            int bi = nb + (s[i] >> ABITS);
            int q = atomicAdd(&lcur[bi], 1);
            sKey[q] = (uint)s[i]; sPay[q] = (uint)d[i]; sBin[q] = (ushort)bi;
        }
    }
    __syncthreads();
    int total = 2 * cnt;
    for (int p = tid; p < total; p += 256) {
        int b = sBin[p];
        int pos = gbase[b] + (p - lstart[b]);
        if (pos < CAPB) binbuf[(size_t)b * CAPB + pos] = make_uint2(sKey[p], sPay[p]);
    }
}

// ---------------- MFMA helper ----------------
__device__ __forceinline__ void stage_w(const ushort* __restrict__ img, ushort* ldsW, int tid)
{
    const uint4* s = (const uint4*)img;
    uint4* d = (uint4*)ldsW;
    #pragma unroll
    for (int i = 0; i < 4; ++i) d[tid + (i << 9)] = s[tid + (i << 9)];
}

// ============ mid: [0, 2nb) csrpass (512 threads) | rest opemb =============================
__global__ __launch_bounds__(512, 2) void mid_kernel(
    const uint2* __restrict__ binbuf, const int* __restrict__ gcur, int nb, int N,
    int* __restrict__ csr_f, int* __restrict__ off_f, int* __restrict__ cnt_f,
    int* __restrict__ csr_i, int* __restrict__ off_i, int* __restrict__ cnt_i,
    const int* __restrict__ ops, const int* __restrict__ params,
    const float* __restrict__ Atab, const float* __restrict__ b1,
    const ushort* __restrict__ W2img, const float* __restrict__ b2,
    ushort* __restrict__ S0)
{
    __shared__ __align__(16) ushort ldsW[16384];
    __shared__ __align__(16) ushort ldsA[16384];
    int tid = threadIdx.x, lane = tid & 63, w = tid >> 6;
    int nb2 = 2 * nb;

    if ((int)blockIdx.x < nb2) {
        // ---- csrpass, 512 threads; scratch overlaid on ldsA ----
        int* hist = (int*)ldsA;          // 512
        int* cur  = hist + 512;          // 512
        int* gsum = cur + 512;           // 8
        int b = blockIdx.x;
        int dir = (b >= nb) ? 1 : 0;
        int binLocal = dir ? b - nb : b;
        int node0 = binLocal << ABITS;
        int nn = min(512, N - node0);
        int total = min(gcur[b], CAPB);
        const uint2* seg = binbuf + (size_t)b * CAPB;
        int* csr = dir ? csr_i : csr_f;
        int* off = dir ? off_i : off_f;
        int* cnt = dir ? cnt_i : cnt_f;

        hist[tid] = 0;
        __syncthreads();
        for (int e = tid; e < total; e += 512) {
            uint2 kp = seg[e];
            atomicAdd(&hist[kp.x - (uint)node0], 1);
        }
        __syncthreads();
        int v = hist[tid];
        int p = v;
        #pragma unroll
        for (int sh = 1; sh < 64; sh <<= 1) { int t = __shfl_up(p, sh, 64); if (lane >= sh) p += t; }
        if (lane == 63) gsum[w] = p;
        __syncthreads();
        if (tid == 0) { int run = 0; for (int g = 0; g < 8; ++g) { int t = gsum[g]; gsum[g] = run; run += t; } }
        __syncthreads();
        int lv = p - v + gsum[w];
        cur[tid] = lv;
        int csrBase = binLocal * CAPB;
        if (tid < nn) { off[node0 + tid] = csrBase + lv; cnt[node0 + tid] = v; }
        __syncthreads();
        int* csrSeg = csr + csrBase;
        for (int e = tid; e < total; e += 512) {
            uint2 kp = seg[e];
            int q = atomicAdd(&cur[kp.x - (uint)node0], 1);
            csrSeg[q] = (int)(kp.y << 8);        // neighbor row BYTE offset
        }
        return;
    }

    // ---- opemb: tables -> lrelu -> @W2+b2, bf16 out ----
    int node0 = ((int)blockIdx.x - nb2) << 7;
    stage_w(W2img, ldsW, tid);

    int r = tid >> 2, sub = tid & 3;      // 4 threads/row, 32 cols each
    int g = node0 + r;
    float4 acc4[8];
    if (g < N) {
        int op = ops[g];
        const float4* T = (const float4*)(Atab + ((size_t)op << 7) + (sub << 5));
        #pragma unroll
        for (int q = 0; q < 8; ++q) acc4[q] = T[q];
        #pragma unroll
        for (int p = 0; p < 4; ++p) {
            int pv = params[(g << 2) + p];
            const float4* Tp = (const float4*)(Atab + ((size_t)((p + 1) * 64 + pv) << 7) + (sub << 5));
            #pragma unroll
            for (int q = 0; q < 8; ++q) {
                float4 u = Tp[q];
                acc4[q].x += u.x; acc4[q].y += u.y; acc4[q].z += u.z; acc4[q].w += u.w;
            }
        }
        const float4* Bv = (const float4*)(b1 + (sub << 5));
        #pragma unroll
        for (int q = 0; q < 8; ++q) {
            float4 bb = Bv[q];
            acc4[q].x = lrelu(acc4[q].x + bb.x);
            acc4[q].y = lrelu(acc4[q].y + bb.y);
            acc4[q].z = lrelu(acc4[q].z + bb.z);
            acc4[q].w = lrelu(acc4[q].w + bb.w);
        }
    } else {
        #pragma unroll
        for (int q = 0; q < 8; ++q) acc4[q] = make_float4(0.f, 0.f, 0.f, 0.f);
    }
    int akey = r & 7;
    #pragma unroll
    for (int q2 = 0; q2 < 4; ++q2) {
        int ch = (sub << 2) + q2;
        float4 a = acc4[q2 * 2], b = acc4[q2 * 2 + 1];
        uint4 pk;
        pk.x = (uint)f2b(a.x) | ((uint)f2b(a.y) << 16);
        pk.y = (uint)f2b(a.z) | ((uint)f2b(a.w) << 16);
        pk.z = (uint)f2b(b.x) | ((uint)f2b(b.y) << 16);
        pk.w = (uint)f2b(b.z) | ((uint)f2b(b.w) << 16);
        *(uint4*)((char*)ldsA + r * 256 + ((ch ^ akey) << 4)) = pk;
    }
    __syncthreads();

    // Swapped-operand MFMA: A = W^T (ldsW), B = h^T (ldsA)
    int l15 = lane & 15, lg = lane >> 4;
    int node = node0 + (w << 4) + l15;
    int brow = (w << 4) + l15;
    const char* Bb = (const char*)ldsA + brow * 256;
    int bkey = (brow & 7) << 4;
    f32x4 acc[8];
    #pragma unroll
    for (int i = 0; i < 8; ++i) acc[i] = f32x4{0.f, 0.f, 0.f, 0.f};
    #pragma unroll
    for (int kk = 0; kk < 4; ++kk) {
        bf16x8 bfr = *(const bf16x8*)(Bb + ((((kk << 2) + lg) << 4) ^ bkey));
        #pragma unroll
        for (int ct = 0; ct < 8; ++ct) {
            int c = (ct << 4) + l15;
            const char* Ab = (const char*)ldsW + c * 256;
            bf16x8 af = *(const bf16x8*)(Ab + ((((kk << 2) + lg) << 4) ^ ((c & 7) << 4)));
            acc[ct] = __builtin_amdgcn_mfma_f32_16x16x32_bf16(af, bfr, acc[ct], 0, 0, 0);
        }
    }
    if (node < N) {
        #pragma unroll
        for (int ct = 0; ct < 8; ++ct) {
            int ch0 = (ct << 4) + (lg << 2);
            float4 bb = *(const float4*)(b2 + ch0);
            uint2 pk;                                   // no lrelu on layer 2
            pk.x = (uint)f2b(acc[ct][0] + bb.x) | ((uint)f2b(acc[ct][1] + bb.y) << 16);
            pk.y = (uint)f2b(acc[ct][2] + bb.z) | ((uint)f2b(acc[ct][3] + bb.w) << 16);
            *(uint2*)((char*)S0 + ((size_t)node << 8) + (ch0 << 1)) = pk;
        }
    }
}

// ---------------- standalone aggregation (both dirs): msg = self + mean(nbrs), bf16 ----------
// Round-8 form (best measured): uint2 loads, 2 neighbors per instruction, byte-offset CSR.
__global__ __launch_bounds__(256, 8) void agg2_kernel(
    const ushort* __restrict__ Sf, const ushort* __restrict__ Si,
    const int* __restrict__ csr_f, const int* __restrict__ off_f, const int* __restrict__ cnt_f,
    const int* __restrict__ csr_i, const int* __restrict__ off_i, const int* __restrict__ cnt_i,
    ushort* __restrict__ msgf, ushort* __restrict__ msgi, int N)
{
    int gw = (blockIdx.x * 256 + threadIdx.x) >> 6;   // one wave per (node, dir)
    int lane = threadIdx.x & 63;
    int dir = 0, g = gw;
    if (g >= N) { dir = 1; g -= N; if (g >= N) return; }
    const char* Sp = (const char*)(dir ? Si : Sf);
    const int* csr = dir ? csr_i : csr_f;
    int off = (dir ? off_i : off_f)[g];
    int deg = (dir ? cnt_i : cnt_f)[g];
    int half = lane >> 5;
    int lb = (lane & 31) << 3;       // byte offset of this lane's uint2 within a row

    float a0 = 0.f, a1 = 0.f, a2 = 0.f, a3 = 0.f;
    int d = 0;
    for (; d + 8 <= deg; d += 8) {                    // 8 neighbors / iter, 4 loads
        int b0 = csr[off + d + 0 + half];
        int b1 = csr[off + d + 2 + half];
        int b2 = csr[off + d + 4 + half];
        int b3 = csr[off + d + 6 + half];
        uint2 v0 = *(const uint2*)(Sp + (uint)(b0 + lb));
        uint2 v1 = *(const uint2*)(Sp + (uint)(b1 + lb));
        uint2 v2 = *(const uint2*)(Sp + (uint)(b2 + lb));
        uint2 v3 = *(const uint2*)(Sp + (uint)(b3 + lb));
        a0 += (lof(v0.x) + lof(v1.x)) + (lof(v2.x) + lof(v3.x));
        a1 += (hif(v0.x) + hif(v1.x)) + (hif(v2.x) + hif(v3.x));
        a2 += (lof(v0.y) + lof(v1.y)) + (lof(v2.y) + lof(v3.y));
        a3 += (hif(v0.y) + hif(v1.y)) + (hif(v2.y) + hif(v3.y));
    }
    for (; d + 2 <= deg; d += 2) {                    // 2 neighbors / iter, 1 load
        int b = csr[off + d + half];
        uint2 v = *(const uint2*)(Sp + (uint)(b + lb));
        a0 += lof(v.x); a1 += hif(v.x); a2 += lof(v.y); a3 += hif(v.y);
    }
    if (d < deg && half == 0) {                       // odd tail: half0 only
        int b = csr[off + d];
        uint2 v = *(const uint2*)(Sp + (uint)(b + lb));
        a0 += lof(v.x); a1 += hif(v.x); a2 += lof(v.y); a3 += hif(v.y);
    }
    a0 += __shfl_xor(a0, 32);
    a1 += __shfl_xor(a1, 32);
    a2 += __shfl_xor(a2, 32);
    a3 += __shfl_xor(a3, 32);
    float invd = 1.0f / fmaxf((float)deg, 1.0f);
    uint2 self = *(const uint2*)(Sp + ((size_t)g << 8) + lb);
    a0 = lof(self.x) + a0 * invd;
    a1 = hif(self.x) + a1 * invd;
    a2 = lof(self.y) + a2 * invd;
    a3 = hif(self.y) + a3 * invd;
    if (half == 0) {
        uint2 pk;
        pk.x = (uint)f2b(a0) | ((uint)f2b(a1) << 16);
        pk.y = (uint)f2b(a2) | ((uint)f2b(a3) << 16);
        *(uint2*)((char*)(dir ? msgi : msgf) + ((size_t)g << 8) + lb) = pk;
    }
}

// ---------------- GIN layer GEMM from msg (both dirs): lrelu(msg @ W + b) ----------------
__global__ __launch_bounds__(512, 8) void gemm2_kernel(
    const ushort* __restrict__ msgf, const ushort* __restrict__ msgi,
    ushort* __restrict__ Sf_out, ushort* __restrict__ Si_out,
    const ushort* __restrict__ Wimg, const float* __restrict__ bias,
    float* __restrict__ colsum, int N)
{
    __shared__ __align__(16) ushort ldsW[16384];
    __shared__ float ldsCS[128];
    int tid = threadIdx.x, lane = tid & 63, w = tid >> 6;
    bool fwd = (blockIdx.x & 1) == 0;
    int node0 = (blockIdx.x >> 1) << 7;
    const ushort* msg = fwd ? msgf : msgi;
    ushort* Sout = fwd ? Sf_out : Si_out;

    stage_w(Wimg, ldsW, tid);
    if (fwd && tid < 128) ldsCS[tid] = 0.f;
    __syncthreads();

    int l15 = lane & 15, lg = lane >> 4;
    int node = node0 + (w << 4) + l15;
    int gr = min(node, N - 1);
    const char* Bb = (const char*)msg + ((size_t)gr << 8);

    f32x4 acc[8];
    #pragma unroll
    for (int i = 0; i < 8; ++i) acc[i] = f32x4{0.f, 0.f, 0.f, 0.f};
    #pragma unroll
    for (int kk = 0; kk < 4; ++kk) {
        bf16x8 bfr = *(const bf16x8*)(Bb + (((kk << 2) + lg) << 4));
        #pragma unroll
        for (int ct = 0; ct < 8; ++ct) {
            int c = (ct << 4) + l15;
            const char* Ab = (const char*)ldsW + c * 256;
            bf16x8 af = *(const bf16x8*)(Ab + ((((kk << 2) + lg) << 4) ^ ((c & 7) << 4)));
            acc[ct] = __builtin_amdgcn_mfma_f32_16x16x32_bf16(af, bfr, acc[ct], 0, 0, 0);
        }
    }

    bool valid = node < N;
    #pragma unroll
    for (int ct = 0; ct < 8; ++ct) {
        int ch0 = (ct << 4) + (lg << 2);
        float4 bb = *(const float4*)(bias + ch0);
        float o0 = lrelu(acc[ct][0] + bb.x);
        float o1 = lrelu(acc[ct][1] + bb.y);
        float o2 = lrelu(acc[ct][2] + bb.z);
        float o3 = lrelu(acc[ct][3] + bb.w);
        if (valid) {
            uint2 pk;
            pk.x = (uint)f2b(o0) | ((uint)f2b(o1) << 16);
            pk.y = (uint)f2b(o2) | ((uint)f2b(o3) << 16);
            *(uint2*)((char*)Sout + ((size_t)node << 8) + (ch0 << 1)) = pk;
        }
        if (fwd) {
            float c0 = valid ? o0 : 0.f, c1 = valid ? o1 : 0.f;
            float c2 = valid ? o2 : 0.f, c3 = valid ? o3 : 0.f;
            #pragma unroll
            for (int m = 1; m < 16; m <<= 1) {
                c0 += __shfl_xor(c0, m);
                c1 += __shfl_xor(c1, m);
                c2 += __shfl_xor(c2, m);
                c3 += __shfl_xor(c3, m);
            }
            if (l15 == 0) {
                atomicAdd(&ldsCS[ch0 + 0], c0);
                atomicAdd(&ldsCS[ch0 + 1], c1);
                atomicAdd(&ldsCS[ch0 + 2], c2);
                atomicAdd(&ldsCS[ch0 + 3], c3);
            }
        }
    }
    if (fwd) {
        __syncthreads();
        if (tid < 128) atomicAdd(&colsum[tid], ldsCS[tid]);
    }
}

// ---------------- graph-level heads (parallel, 512 threads, runs as one out2 block) --------
__device__ __forceinline__ void final_body(
    float* lds, const float* __restrict__ convsum,
    const float* __restrict__ mw1, const float* __restrict__ mb1,
    const float* __restrict__ mw2, const float* __restrict__ mb2,
    const float* __restrict__ iw1, const float* __restrict__ ib1,
    const float* __restrict__ iw2, const float* __restrict__ ib2,
    const float* __restrict__ cw, const float* __restrict__ cb,
    float* __restrict__ out1)
{
    float* x  = lds;          // 384
    float* pa = lds + 384;    // 512
    float* pb = lds + 896;    // 512
    float* t1 = lds + 1408;   // 128
    float* t2 = lds + 1536;   // 128
    int tid = threadIdx.x, j = tid & 127, s = tid >> 7;   // 4 k-slices
    if (tid < 384) x[tid] = convsum[tid];
    __syncthreads();
    float a = 0.f, c = 0.f;
    for (int k = s * 96; k < s * 96 + 96; ++k) {
        a += x[k] * mw1[k * 128 + j];
        c += x[256 + (k & 127)] * iw1[k * 128 + j];
    }
    pa[tid] = a; pb[tid] = c;
    __syncthreads();
    if (s == 0) {
        t1[j] = lrelu(pa[j] + pa[128 + j] + pa[256 + j] + pa[384 + j] + mb1[j]);
        t2[j] = lrelu(pb[j] + pb[128 + j] + pb[256 + j] + pb[384 + j] + ib1[j]);
    }
    __syncthreads();
    float b = 0.f, d = 0.f;
    for (int k = s * 32; k < s * 32 + 32; ++k) {
        b += t1[k] * mw2[k * 128 + j];
        d += t2[k] * iw2[k * 128 + j];
    }
    pa[tid] = b; pb[tid] = d;
    __syncthreads();
    if (s == 0) {
        t1[j] = pa[j] + pa[128 + j] + pa[256 + j] + pa[384 + j] + mb2[j];   // g1
        t2[j] = pb[j] + pb[128 + j] + pb[256 + j] + pb[384 + j] + ib2[j];   // g2
    }
    __syncthreads();
    float e = 0.f;
    for (int k = s * 32; k < s * 32 + 32; ++k)
        e += t1[k] * cw[k * 128 + j] + t2[k] * cw[(128 + k) * 128 + j];
    pa[tid] = e;
    __syncthreads();
    if (s == 0) out1[j] = pa[j] + pa[128 + j] + pa[256 + j] + pa[384 + j] + cb[j];
}

// ---------------- out2 = [Sf | Si] @ comb_w + comb_b (fp32 out) + final block --------------
__global__ __launch_bounds__(512, 4) void out2_fused(
    const ushort* __restrict__ Sf, const ushort* __restrict__ Si,
    const ushort* __restrict__ CWimg, const float* __restrict__ cb,
    float* __restrict__ out, int gemmBlocks, int N,
    const float* __restrict__ convsum,
    const float* __restrict__ mw1, const float* __restrict__ mb1,
    const float* __restrict__ mw2, const float* __restrict__ mb2,
    const float* __restrict__ iw1, const float* __restrict__ ib1,
    const float* __restrict__ iw2, const float* __restrict__ ib2,
    const float* __restrict__ cw, float* __restrict__ out1)
{
    __shared__ __align__(16) ushort ldsW[16384];
    int tid = threadIdx.x, lane = tid & 63, w = tid >> 6;
    if ((int)blockIdx.x >= gemmBlocks) {
        final_body((float*)ldsW, convsum, mw1, mb1, mw2, mb2,
                   iw1, ib1, iw2, ib2, cw, cb, out1);
        return;
    }
    int node0 = blockIdx.x << 7;
    int l15 = lane & 15, lg = lane >> 4;
    int node = node0 + (w << 4) + l15;
    int gr = min(node, N - 1);
    f32x4 acc[8];
    #pragma unroll
    for (int i = 0; i < 8; ++i) acc[i] = f32x4{0.f, 0.f, 0.f, 0.f};
    #pragma unroll
    for (int pass = 0; pass < 2; ++pass) {
        if (pass) __syncthreads();
        stage_w(CWimg + (pass << 14), ldsW, tid);
        __syncthreads();
        const char* Bb = (const char*)(pass ? Si : Sf) + ((size_t)gr << 8);
        #pragma unroll
        for (int kk = 0; kk < 4; ++kk) {
            bf16x8 bfr = *(const bf16x8*)(Bb + (((kk << 2) + lg) << 4));
            #pragma unroll
            for (int ct = 0; ct < 8; ++ct) {
                int c = (ct << 4) + l15;
                const char* Ab = (const char*)ldsW + c * 256;
                bf16x8 af = *(const bf16x8*)(Ab + ((((kk << 2) + lg) << 4) ^ ((c & 7) << 4)));
                acc[ct] = __builtin_amdgcn_mfma_f32_16x16x32_bf16(af, bfr, acc[ct], 0, 0, 0);
            }
        }
    }
    if (node < N) {
        #pragma unroll
        for (int ct = 0; ct < 8; ++ct) {
            int ch0 = (ct << 4) + (lg << 2);
            float4 bb = *(const float4*)(cb + ch0);
            float4 o;
            o.x = acc[ct][0] + bb.x;
            o.y = acc[ct][1] + bb.y;
            o.z = acc[ct][2] + bb.z;
            o.w = acc[ct][3] + bb.w;
            *(float4*)(out + (size_t)node * 128 + ch0) = o;
        }
    }
}

extern "C" void kernel_launch(void* const* d_in, const int* in_sizes, int n_in,
                              void* d_out, int out_size, void* d_ws, size_t ws_size,
                              hipStream_t stream)
{
    (void)n_in; (void)out_size; (void)ws_size;
    const int*   ops    = (const int*)d_in[0];
    const int*   params = (const int*)d_in[1];
    const int*   esrc   = (const int*)d_in[2];
    const int*   edst   = (const int*)d_in[3];
    const float* opT    = (const float*)d_in[4];
    const float* parT   = (const float*)d_in[5];
    const float* ow1    = (const float*)d_in[6];
    const float* ob1    = (const float*)d_in[7];
    const float* ow2    = (const float*)d_in[8];
    const float* ob2    = (const float*)d_in[9];
    const float* convw  = (const float*)d_in[10];
    const float* convb  = (const float*)d_in[11];
    const float* mw1    = (const float*)d_in[12];
    const float* mb1    = (const float*)d_in[13];
    const float* mw2    = (const float*)d_in[14];
    const float* mb2    = (const float*)d_in[15];
    const float* iw1    = (const float*)d_in[16];
    const float* ib1    = (const float*)d_in[17];
    const float* iw2    = (const float*)d_in[18];
    const float* ib2    = (const float*)d_in[19];
    const float* cw     = (const float*)d_in[20];
    const float* cb     = (const float*)d_in[21];

    const int N = in_sizes[0];      // 100000
    const int E = in_sizes[2];      // 1600000
    const int nb = (N + 511) >> ABITS;   // 196 bins per direction
    const size_t NP = (size_t)N * 128;

    // workspace layout (~162 MB)
    ushort* S0   = (ushort*)d_ws;                    // [N][128] bf16
    ushort* S1   = S0 + NP;
    ushort* S2   = S1 + NP;
    ushort* S3   = S2 + NP;
    ushort* Wt   = S3 + NP;                          // 6 * 16384 bf16 images
    float*  Atab = (float*)(Wt + 6 * 16384);         // 320*128 fp32
    float*  convsum = Atab + 320 * 128;              // 384 used, 512 reserved
    int*    gcur = (int*)(convsum + 512);            // 2*nb used, 512 reserved
    uint2*  binbuf = (uint2*)(gcur + 512);           // 2*nb*CAPB entries
    int*    csr_f = (int*)(binbuf + (size_t)2 * nb * CAPB);   // nb*CAPB
    int*    csr_i = csr_f + (size_t)nb * CAPB;
    int*    off_f = csr_i + (size_t)nb * CAPB;       // N each
    int*    cnt_f = off_f + N;
    int*    off_i = cnt_f + N;
    int*    cnt_i = off_i + N;

    float* out1 = (float*)d_out;
    float* out2 = out1 + 128;
    // msg buffers live in the (dead until the end) out2 region
    ushort* MSGF = (ushort*)out2;
    ushort* MSGI = MSGF + NP;

    hipMemsetAsync(convsum, 0, sizeof(float) * 1024, stream);   // convsum + gcur

    const int nChunks = (E + CHUNK - 1) / CHUNK;     // 782
    // buildprep: binpass (782) | tables (160) | prep_w (384)
    buildprep_kernel<<<nChunks + 160 + 384, 256, 0, stream>>>(
        esrc, edst, E, nb, nChunks, gcur, binbuf,
        opT, parT, ow1, Atab, convw, ow2, cw, Wt);

    const int grid = (N + 127) / 128;          // 782
    // mid: csrpass (2*nb) | opemb (782)
    mid_kernel<<<2 * nb + grid, 512, 0, stream>>>(
        binbuf, gcur, nb, N,
        csr_f, off_f, cnt_f, csr_i, off_i, cnt_i,
        ops, params, Atab, ob1, Wt + 3 * 16384, ob2, S0);

    const int aggGrid = (2 * N + 3) / 4;   // one wave per (node, dir)
    // layer 0: fwd S0->S1 (colsum), inv S0->S3   [layer-0 dedup: both read S0]
    agg2_kernel<<<aggGrid, 256, 0, stream>>>(S0, S0, csr_f, off_f, cnt_f, csr_i, off_i, cnt_i, MSGF, MSGI, N);
    gemm2_kernel<<<2 * grid, 512, 0, stream>>>(MSGF, MSGI, S1, S3, Wt,             convb,       convsum,       N);
    // layer 1: fwd S1->S0, inv S3->S2
    agg2_kernel<<<aggGrid, 256, 0, stream>>>(S1, S3, csr_f, off_f, cnt_f, csr_i, off_i, cnt_i, MSGF, MSGI, N);
    gemm2_kernel<<<2 * grid, 512, 0, stream>>>(MSGF, MSGI, S0, S2, Wt + 16384,     convb + 128, convsum + 128, N);
    // layer 2: fwd S0->S1, inv S2->S3
    agg2_kernel<<<aggGrid, 256, 0, stream>>>(S0, S2, csr_f, off_f, cnt_f, csr_i, off_i, cnt_i, MSGF, MSGI, N);
    gemm2_kernel<<<2 * grid, 512, 0, stream>>>(MSGF, MSGI, S1, S3, Wt + 2 * 16384, convb + 256, convsum + 256, N);

    // out2 (782 gemm blocks) + final head (1 extra block, overlapped)
    out2_fused<<<grid + 1, 512, 0, stream>>>(S1, S3, Wt + 4 * 16384, cb, out2, grid, N,
                                             convsum, mw1, mb1, mw2, mb2,
                                             iw1, ib1, iw2, ib2, cw, out1);
}

// Round 11
// 599.550 us; speedup vs baseline: 1.4834x; 1.0930x over previous
//
#include <hip/hip_runtime.h>

// SemaEmb GIN network — round 11: GEMM fused into agg via LDS msg (no global msg
// round-trip), 8-way-replicated colsum atomics. Gather body = round-8 (best measured).
// N=100000, E=1600000, EMB=128, L=3, P=4.

typedef unsigned int  uint;
typedef unsigned short ushort;
typedef float  f32x4  __attribute__((ext_vector_type(4)));
typedef short  bf16x8 __attribute__((ext_vector_type(8)));

#define ABITS 9          // 512 nodes per bin
#define CAPB  12288      // entries per bin segment
#define CHUNK 2048       // edges per binpass block

__device__ __forceinline__ float lrelu(float x) { return x > 0.0f ? x : 0.01f * x; }
__device__ __forceinline__ ushort f2b(float x) {
    uint u = __float_as_uint(x);
    return (ushort)((u + 0x7fffu + ((u >> 16) & 1u)) >> 16);
}
__device__ __forceinline__ float lof(uint u) { return __uint_as_float(u << 16); }
__device__ __forceinline__ float hif(uint u) { return __uint_as_float(u & 0xffff0000u); }

// ============ buildprep: [0,nChunks) binpass | [nChunks,+160) tables | rest prep_w =========
__global__ __launch_bounds__(256) void buildprep_kernel(
    const int* __restrict__ esrc, const int* __restrict__ edst, int E, int nb, int nChunks,
    int* __restrict__ gcur, uint2* __restrict__ binbuf,
    const float* __restrict__ opT, const float* __restrict__ parT,
    const float* __restrict__ W1, float* __restrict__ Atab,
    const float* __restrict__ convw, const float* __restrict__ ow2,
    const float* __restrict__ cw, ushort* __restrict__ Wt)
{
    __shared__ int hist[448];
    __shared__ int lstart[448];
    __shared__ int gbase[448];
    __shared__ int lcur[448];
    __shared__ int gsum[8];
    __shared__ uint sKey[CHUNK * 2];
    __shared__ uint sPay[CHUNK * 2];
    __shared__ ushort sBin[CHUNK * 2];
    int tid = threadIdx.x, lane = tid & 63;

    if ((int)blockIdx.x >= nChunks) {
        int rb = (int)blockIdx.x - nChunks;
        if (rb < 160) {
            int b = (rb << 1) | (tid >> 7);
            int t = b >> 6, v = b & 63, j = tid & 127;
            const float* emb = (t == 0 ? opT : parT) + v * 128;
            const float* w = W1 + (size_t)t * 128 * 128;
            float acc = 0.f;
            for (int k = 0; k < 128; ++k) acc += emb[k] * w[k * 128 + j];
            Atab[(size_t)b * 128 + j] = acc;
        } else {
            int t = (rb - 160) * 256 + tid;
            int img = t >> 14, idx = t & 16383;
            int k = idx >> 7, c = idx & 127;
            const float* src;
            if (img < 3)       src = convw + img * 16384;
            else if (img == 3) src = ow2;
            else               src = cw + (img - 4) * 16384;
            float v = src[k * 128 + c];
            int byteoff = (img << 15) + (c << 8) + ((((k >> 3) ^ (c & 7)) << 4)) + ((k & 7) << 1);
            Wt[byteoff >> 1] = f2b(v);
        }
        return;
    }

    int nb2 = nb * 2;
    int base = (int)blockIdx.x * CHUNK;
    int cnt = min(CHUNK, E - base);
    for (int i = tid; i < 448; i += 256) hist[i] = 0;
    __syncthreads();
    int s[8], d[8];
    #pragma unroll
    for (int i = 0; i < 8; ++i) {
        int idx = i * 256 + tid;
        if (idx < cnt) {
            s[i] = esrc[base + idx];
            d[i] = edst[base + idx];
            atomicAdd(&hist[d[i] >> ABITS], 1);
            atomicAdd(&hist[nb + (s[i] >> ABITS)], 1);
        } else s[i] = -1;
    }
    __syncthreads();
    #pragma unroll
    for (int k = 0; k < 2; ++k) {
        int idx = k * 256 + tid;
        int v = (idx < 448) ? hist[idx] : 0;
        int p = v;
        #pragma unroll
        for (int sh = 1; sh < 64; sh <<= 1) { int t = __shfl_up(p, sh, 64); if (lane >= sh) p += t; }
        if (idx < 448) {
            lstart[idx] = p - v;
            if (lane == 63) gsum[idx >> 6] = p;
        }
    }
    __syncthreads();
    if (tid == 0) { int run = 0; for (int g = 0; g < 7; ++g) { int t = gsum[g]; gsum[g] = run; run += t; } }
    __syncthreads();
    #pragma unroll
    for (int k = 0; k < 2; ++k) {
        int idx = k * 256 + tid;
        if (idx < 448) lstart[idx] += gsum[idx >> 6];
    }
    __syncthreads();
    for (int i = tid; i < nb2; i += 256) {
        int h = hist[i];
        gbase[i] = h ? atomicAdd(&gcur[i], h) : 0;
        lcur[i] = lstart[i];
    }
    __syncthreads();
    #pragma unroll
    for (int i = 0; i < 8; ++i) {
        if (s[i] >= 0) {
            int bf = d[i] >> ABITS;
            int p = atomicAdd(&lcur[bf], 1);
            sKey[p] = (uint)d[i]; sPay[p] = (uint)s[i]; sBin[p] = (ushort)bf;
            int bi = nb + (s[i] >> ABITS);
            int q = atomicAdd(&lcur[bi], 1);
            sKey[q] = (uint)s[i]; sPay[q] = (uint)d[i]; sBin[q] = (ushort)bi;
        }
    }
    __syncthreads();
    int total = 2 * cnt;
    for (int p = tid; p < total; p += 256) {
        int b = sBin[p];
        int pos = gbase[b] + (p - lstart[b]);
        if (pos < CAPB) binbuf[(size_t)b * CAPB + pos] = make_uint2(sKey[p], sPay[p]);
    }
}

// ---------------- MFMA helper ----------------
__device__ __forceinline__ void stage_w(const ushort* __restrict__ img, ushort* ldsW, int tid)
{
    const uint4* s = (const uint4*)img;
    uint4* d = (uint4*)ldsW;
    #pragma unroll
    for (int i = 0; i < 4; ++i) d[tid + (i << 9)] = s[tid + (i << 9)];
}

// ============ mid: [0, 2nb) csrpass (512 threads) | rest opemb =============================
__global__ __launch_bounds__(512, 2) void mid_kernel(
    const uint2* __restrict__ binbuf, const int* __restrict__ gcur, int nb, int N,
    int* __restrict__ csr_f, int* __restrict__ off_f, int* __restrict__ cnt_f,
    int* __restrict__ csr_i, int* __restrict__ off_i, int* __restrict__ cnt_i,
    const int* __restrict__ ops, const int* __restrict__ params,
    const float* __restrict__ Atab, const float* __restrict__ b1,
    const ushort* __restrict__ W2img, const float* __restrict__ b2,
    ushort* __restrict__ S0)
{
    __shared__ __align__(16) ushort ldsW[16384];
    __shared__ __align__(16) ushort ldsA[16384];
    int tid = threadIdx.x, lane = tid & 63, w = tid >> 6;
    int nb2 = 2 * nb;

    if ((int)blockIdx.x < nb2) {
        int* hist = (int*)ldsA;          // 512
        int* cur  = hist + 512;          // 512
        int* gsum = cur + 512;           // 8
        int b = blockIdx.x;
        int dir = (b >= nb) ? 1 : 0;
        int binLocal = dir ? b - nb : b;
        int node0 = binLocal << ABITS;
        int nn = min(512, N - node0);
        int total = min(gcur[b], CAPB);
        const uint2* seg = binbuf + (size_t)b * CAPB;
        int* csr = dir ? csr_i : csr_f;
        int* off = dir ? off_i : off_f;
        int* cnt = dir ? cnt_i : cnt_f;

        hist[tid] = 0;
        __syncthreads();
        for (int e = tid; e < total; e += 512) {
            uint2 kp = seg[e];
            atomicAdd(&hist[kp.x - (uint)node0], 1);
        }
        __syncthreads();
        int v = hist[tid];
        int p = v;
        #pragma unroll
        for (int sh = 1; sh < 64; sh <<= 1) { int t = __shfl_up(p, sh, 64); if (lane >= sh) p += t; }
        if (lane == 63) gsum[w] = p;
        __syncthreads();
        if (tid == 0) { int run = 0; for (int g = 0; g < 8; ++g) { int t = gsum[g]; gsum[g] = run; run += t; } }
        __syncthreads();
        int lv = p - v + gsum[w];
        cur[tid] = lv;
        int csrBase = binLocal * CAPB;
        if (tid < nn) { off[node0 + tid] = csrBase + lv; cnt[node0 + tid] = v; }
        __syncthreads();
        int* csrSeg = csr + csrBase;
        for (int e = tid; e < total; e += 512) {
            uint2 kp = seg[e];
            int q = atomicAdd(&cur[kp.x - (uint)node0], 1);
            csrSeg[q] = (int)(kp.y << 8);        // neighbor row BYTE offset
        }
        return;
    }

    // ---- opemb ----
    int node0 = ((int)blockIdx.x - nb2) << 7;
    stage_w(W2img, ldsW, tid);

    int r = tid >> 2, sub = tid & 3;
    int g = node0 + r;
    float4 acc4[8];
    if (g < N) {
        int op = ops[g];
        const float4* T = (const float4*)(Atab + ((size_t)op << 7) + (sub << 5));
        #pragma unroll
        for (int q = 0; q < 8; ++q) acc4[q] = T[q];
        #pragma unroll
        for (int p = 0; p < 4; ++p) {
            int pv = params[(g << 2) + p];
            const float4* Tp = (const float4*)(Atab + ((size_t)((p + 1) * 64 + pv) << 7) + (sub << 5));
            #pragma unroll
            for (int q = 0; q < 8; ++q) {
                float4 u = Tp[q];
                acc4[q].x += u.x; acc4[q].y += u.y; acc4[q].z += u.z; acc4[q].w += u.w;
            }
        }
        const float4* Bv = (const float4*)(b1 + (sub << 5));
        #pragma unroll
        for (int q = 0; q < 8; ++q) {
            float4 bb = Bv[q];
            acc4[q].x = lrelu(acc4[q].x + bb.x);
            acc4[q].y = lrelu(acc4[q].y + bb.y);
            acc4[q].z = lrelu(acc4[q].z + bb.z);
            acc4[q].w = lrelu(acc4[q].w + bb.w);
        }
    } else {
        #pragma unroll
        for (int q = 0; q < 8; ++q) acc4[q] = make_float4(0.f, 0.f, 0.f, 0.f);
    }
    int akey = r & 7;
    #pragma unroll
    for (int q2 = 0; q2 < 4; ++q2) {
        int ch = (sub << 2) + q2;
        float4 a = acc4[q2 * 2], b = acc4[q2 * 2 + 1];
        uint4 pk;
        pk.x = (uint)f2b(a.x) | ((uint)f2b(a.y) << 16);
        pk.y = (uint)f2b(a.z) | ((uint)f2b(a.w) << 16);
        pk.z = (uint)f2b(b.x) | ((uint)f2b(b.y) << 16);
        pk.w = (uint)f2b(b.z) | ((uint)f2b(b.w) << 16);
        *(uint4*)((char*)ldsA + r * 256 + ((ch ^ akey) << 4)) = pk;
    }
    __syncthreads();

    int l15 = lane & 15, lg = lane >> 4;
    int node = node0 + (w << 4) + l15;
    int brow = (w << 4) + l15;
    const char* Bb = (const char*)ldsA + brow * 256;
    int bkey = (brow & 7) << 4;
    f32x4 acc[8];
    #pragma unroll
    for (int i = 0; i < 8; ++i) acc[i] = f32x4{0.f, 0.f, 0.f, 0.f};
    #pragma unroll
    for (int kk = 0; kk < 4; ++kk) {
        bf16x8 bfr = *(const bf16x8*)(Bb + ((((kk << 2) + lg) << 4) ^ bkey));
        #pragma unroll
        for (int ct = 0; ct < 8; ++ct) {
            int c = (ct << 4) + l15;
            const char* Ab = (const char*)ldsW + c * 256;
            bf16x8 af = *(const bf16x8*)(Ab + ((((kk << 2) + lg) << 4) ^ ((c & 7) << 4)));
            acc[ct] = __builtin_amdgcn_mfma_f32_16x16x32_bf16(af, bfr, acc[ct], 0, 0, 0);
        }
    }
    if (node < N) {
        #pragma unroll
        for (int ct = 0; ct < 8; ++ct) {
            int ch0 = (ct << 4) + (lg << 2);
            float4 bb = *(const float4*)(b2 + ch0);
            uint2 pk;                                   // no lrelu on layer 2
            pk.x = (uint)f2b(acc[ct][0] + bb.x) | ((uint)f2b(acc[ct][1] + bb.y) << 16);
            pk.y = (uint)f2b(acc[ct][2] + bb.z) | ((uint)f2b(acc[ct][3] + bb.w) << 16);
            *(uint2*)((char*)S0 + ((size_t)node << 8) + (ch0 << 1)) = pk;
        }
    }
}

// ============ glayer: fused agg (round-8 gather) + MFMA GEMM via LDS msg ===================
// Block = 4 waves = 16 nodes, one direction (fwd blocks first). Each wave gathers 4 nodes
// into LDS msg rows (272B stride), one barrier, then computes 2 of 8 ct-blocks of
// lrelu(msg @ W + b) for all 16 nodes (gemm2's MFMA, B-frags from LDS, W from global image).
__global__ __launch_bounds__(256, 8) void glayer_kernel(
    const ushort* __restrict__ Sf_in, const ushort* __restrict__ Si_in,
    ushort* __restrict__ Sf_out, ushort* __restrict__ Si_out,
    const int* __restrict__ csr_f, const int* __restrict__ off_f, const int* __restrict__ cnt_f,
    const int* __restrict__ csr_i, const int* __restrict__ off_i, const int* __restrict__ cnt_i,
    const ushort* __restrict__ Wimg, const float* __restrict__ bias,
    float* __restrict__ colsumR, int nBlkF, int N)
{
    __shared__ __align__(16) char msgL[16 * 272];
    __shared__ float ldsCS[128];
    int tid = threadIdx.x, lane = tid & 63, w = tid >> 6;
    bool fwd = (int)blockIdx.x < nBlkF;
    int blkLocal = fwd ? (int)blockIdx.x : (int)blockIdx.x - nBlkF;
    const char* Sp = (const char*)(fwd ? Sf_in : Si_in);
    ushort* Sout = fwd ? Sf_out : Si_out;
    const int* csr  = fwd ? csr_f : csr_i;
    const int* offA = fwd ? off_f : off_i;
    const int* cntA = fwd ? cnt_f : cnt_i;

    if (tid < 128) ldsCS[tid] = 0.f;

    int half = lane >> 5;
    int lb = (lane & 31) << 3;       // byte offset of this lane's uint2 within a row
    int node0 = blkLocal << 4;

    #pragma unroll
    for (int i = 0; i < 4; ++i) {
        int g = node0 + (w << 2) + i;
        float a0 = 0.f, a1 = 0.f, a2 = 0.f, a3 = 0.f;
        if (g < N) {
            int off = offA[g], deg = cntA[g];
            int d = 0;
            for (; d + 8 <= deg; d += 8) {                    // 8 nbrs / iter, 4 loads
                int b0 = csr[off + d + 0 + half];
                int b1 = csr[off + d + 2 + half];
                int b2 = csr[off + d + 4 + half];
                int b3 = csr[off + d + 6 + half];
                uint2 v0 = *(const uint2*)(Sp + (uint)(b0 + lb));
                uint2 v1 = *(const uint2*)(Sp + (uint)(b1 + lb));
                uint2 v2 = *(const uint2*)(Sp + (uint)(b2 + lb));
                uint2 v3 = *(const uint2*)(Sp + (uint)(b3 + lb));
                a0 += (lof(v0.x) + lof(v1.x)) + (lof(v2.x) + lof(v3.x));
                a1 += (hif(v0.x) + hif(v1.x)) + (hif(v2.x) + hif(v3.x));
                a2 += (lof(v0.y) + lof(v1.y)) + (lof(v2.y) + lof(v3.y));
                a3 += (hif(v0.y) + hif(v1.y)) + (hif(v2.y) + hif(v3.y));
            }
            for (; d + 2 <= deg; d += 2) {                    // 2 nbrs / iter, 1 load
                int b = csr[off + d + half];
                uint2 v = *(const uint2*)(Sp + (uint)(b + lb));
                a0 += lof(v.x); a1 += hif(v.x); a2 += lof(v.y); a3 += hif(v.y);
            }
            if (d < deg && half == 0) {                       // odd tail: half0 only
                int b = csr[off + d];
                uint2 v = *(const uint2*)(Sp + (uint)(b + lb));
                a0 += lof(v.x); a1 += hif(v.x); a2 += lof(v.y); a3 += hif(v.y);
            }
            a0 += __shfl_xor(a0, 32);
            a1 += __shfl_xor(a1, 32);
            a2 += __shfl_xor(a2, 32);
            a3 += __shfl_xor(a3, 32);
            float iv = 1.0f / fmaxf((float)deg, 1.0f);
            uint2 self = *(const uint2*)(Sp + ((size_t)g << 8) + lb);
            a0 = lof(self.x) + a0 * iv;
            a1 = hif(self.x) + a1 * iv;
            a2 = lof(self.y) + a2 * iv;
            a3 = hif(self.y) + a3 * iv;
        }
        if (half == 0) {
            uint2 pk;
            pk.x = (uint)f2b(a0) | ((uint)f2b(a1) << 16);
            pk.y = (uint)f2b(a2) | ((uint)f2b(a3) << 16);
            *(uint2*)(msgL + ((w << 2) + i) * 272 + lb) = pk;
        }
    }
    __syncthreads();

    // MFMA: rows = 16 LDS msg rows (node node0+l15), wave handles ct blocks {2w, 2w+1}
    int l15 = lane & 15, lg = lane >> 4;
    const char* Bb = msgL + l15 * 272;
    f32x4 acc0 = f32x4{0.f, 0.f, 0.f, 0.f};
    f32x4 acc1 = f32x4{0.f, 0.f, 0.f, 0.f};
    int ct0 = w << 1;
    int c0 = (ct0 << 4) + l15;
    int c1 = ((ct0 + 1) << 4) + l15;
    const char* A0 = (const char*)Wimg + c0 * 256;
    const char* A1 = (const char*)Wimg + c1 * 256;
    int k0 = (c0 & 7) << 4, k1 = (c1 & 7) << 4;
    #pragma unroll
    for (int kk = 0; kk < 4; ++kk) {
        int chk = ((kk << 2) + lg) << 4;
        bf16x8 bfr = *(const bf16x8*)(Bb + chk);
        bf16x8 af0 = *(const bf16x8*)(A0 + (chk ^ k0));
        bf16x8 af1 = *(const bf16x8*)(A1 + (chk ^ k1));
        acc0 = __builtin_amdgcn_mfma_f32_16x16x32_bf16(af0, bfr, acc0, 0, 0, 0);
        acc1 = __builtin_amdgcn_mfma_f32_16x16x32_bf16(af1, bfr, acc1, 0, 0, 0);
    }

    int gs = node0 + l15;
    bool valid = gs < N;
    #pragma unroll
    for (int q = 0; q < 2; ++q) {
        f32x4 a = q ? acc1 : acc0;
        int ch0 = ((ct0 + q) << 4) + (lg << 2);
        float4 bb = *(const float4*)(bias + ch0);
        float o0 = lrelu(a[0] + bb.x);
        float o1 = lrelu(a[1] + bb.y);
        float o2 = lrelu(a[2] + bb.z);
        float o3 = lrelu(a[3] + bb.w);
        if (valid) {
            uint2 pk;
            pk.x = (uint)f2b(o0) | ((uint)f2b(o1) << 16);
            pk.y = (uint)f2b(o2) | ((uint)f2b(o3) << 16);
            *(uint2*)((char*)Sout + ((size_t)gs << 8) + (ch0 << 1)) = pk;
        }
        if (fwd) {
            float s0 = valid ? o0 : 0.f, s1 = valid ? o1 : 0.f;
            float s2 = valid ? o2 : 0.f, s3 = valid ? o3 : 0.f;
            #pragma unroll
            for (int m = 1; m < 16; m <<= 1) {       // reduce over the 16 node-lanes
                s0 += __shfl_xor(s0, m);
                s1 += __shfl_xor(s1, m);
                s2 += __shfl_xor(s2, m);
                s3 += __shfl_xor(s3, m);
            }
            if (l15 == 0) {
                atomicAdd(&ldsCS[ch0 + 0], s0);
                atomicAdd(&ldsCS[ch0 + 1], s1);
                atomicAdd(&ldsCS[ch0 + 2], s2);
                atomicAdd(&ldsCS[ch0 + 3], s3);
            }
        }
    }
    if (fwd) {
        __syncthreads();
        if (tid < 128) atomicAdd(&colsumR[(((int)blockIdx.x & 7) << 7) + tid], ldsCS[tid]);
    }
}

// ---------------- graph-level heads (parallel, 512 threads, runs as one out2 block) --------
__device__ __forceinline__ void final_body(
    float* lds, const float* __restrict__ convsum,
    const float* __restrict__ mw1, const float* __restrict__ mb1,
    const float* __restrict__ mw2, const float* __restrict__ mb2,
    const float* __restrict__ iw1, const float* __restrict__ ib1,
    const float* __restrict__ iw2, const float* __restrict__ ib2,
    const float* __restrict__ cw, const float* __restrict__ cb,
    float* __restrict__ out1)
{
    float* x  = lds;          // 384
    float* pa = lds + 384;    // 512
    float* pb = lds + 896;    // 512
    float* t1 = lds + 1408;   // 128
    float* t2 = lds + 1536;   // 128
    int tid = threadIdx.x, j = tid & 127, s = tid >> 7;   // 4 k-slices
    if (tid < 384) {
        const float* cs = convsum + (((size_t)(tid >> 7)) << 10) + (tid & 127);
        float acc = 0.f;
        #pragma unroll
        for (int r = 0; r < 8; ++r) acc += cs[r << 7];    // sum 8 replicas
        x[tid] = acc;
    }
    __syncthreads();
    float a = 0.f, c = 0.f;
    for (int k = s * 96; k < s * 96 + 96; ++k) {
        a += x[k] * mw1[k * 128 + j];
        c += x[256 + (k & 127)] * iw1[k * 128 + j];
    }
    pa[tid] = a; pb[tid] = c;
    __syncthreads();
    if (s == 0) {
        t1[j] = lrelu(pa[j] + pa[128 + j] + pa[256 + j] + pa[384 + j] + mb1[j]);
        t2[j] = lrelu(pb[j] + pb[128 + j] + pb[256 + j] + pb[384 + j] + ib1[j]);
    }
    __syncthreads();
    float b = 0.f, d = 0.f;
    for (int k = s * 32; k < s * 32 + 32; ++k) {
        b += t1[k] * mw2[k * 128 + j];
        d += t2[k] * iw2[k * 128 + j];
    }
    pa[tid] = b; pb[tid] = d;
    __syncthreads();
    if (s == 0) {
        t1[j] = pa[j] + pa[128 + j] + pa[256 + j] + pa[384 + j] + mb2[j];   // g1
        t2[j] = pb[j] + pb[128 + j] + pb[256 + j] + pb[384 + j] + ib2[j];   // g2
    }
    __syncthreads();
    float e = 0.f;
    for (int k = s * 32; k < s * 32 + 32; ++k)
        e += t1[k] * cw[k * 128 + j] + t2[k] * cw[(128 + k) * 128 + j];
    pa[tid] = e;
    __syncthreads();
    if (s == 0) out1[j] = pa[j] + pa[128 + j] + pa[256 + j] + pa[384 + j] + cb[j];
}

// ---------------- out2 = [Sf | Si] @ comb_w + comb_b (fp32 out) + final block --------------
__global__ __launch_bounds__(512, 4) void out2_fused(
    const ushort* __restrict__ Sf, const ushort* __restrict__ Si,
    const ushort* __restrict__ CWimg, const float* __restrict__ cb,
    float* __restrict__ out, int gemmBlocks, int N,
    const float* __restrict__ convsum,
    const float* __restrict__ mw1, const float* __restrict__ mb1,
    const float* __restrict__ mw2, const float* __restrict__ mb2,
    const float* __restrict__ iw1, const float* __restrict__ ib1,
    const float* __restrict__ iw2, const float* __restrict__ ib2,
    const float* __restrict__ cw, float* __restrict__ out1)
{
    __shared__ __align__(16) ushort ldsW[16384];
    int tid = threadIdx.x, lane = tid & 63, w = tid >> 6;
    if ((int)blockIdx.x >= gemmBlocks) {
        final_body((float*)ldsW, convsum, mw1, mb1, mw2, mb2,
                   iw1, ib1, iw2, ib2, cw, cb, out1);
        return;
    }
    int node0 = blockIdx.x << 7;
    int l15 = lane & 15, lg = lane >> 4;
    int node = node0 + (w << 4) + l15;
    int gr = min(node, N - 1);
    f32x4 acc[8];
    #pragma unroll
    for (int i = 0; i < 8; ++i) acc[i] = f32x4{0.f, 0.f, 0.f, 0.f};
    #pragma unroll
    for (int pass = 0; pass < 2; ++pass) {
        if (pass) __syncthreads();
        stage_w(CWimg + (pass << 14), ldsW, tid);
        __syncthreads();
        const char* Bb = (const char*)(pass ? Si : Sf) + ((size_t)gr << 8);
        #pragma unroll
        for (int kk = 0; kk < 4; ++kk) {
            bf16x8 bfr = *(const bf16x8*)(Bb + (((kk << 2) + lg) << 4));
            #pragma unroll
            for (int ct = 0; ct < 8; ++ct) {
                int c = (ct << 4) + l15;
                const char* Ab = (const char*)ldsW + c * 256;
                bf16x8 af = *(const bf16x8*)(Ab + ((((kk << 2) + lg) << 4) ^ ((c & 7) << 4)));
                acc[ct] = __builtin_amdgcn_mfma_f32_16x16x32_bf16(af, bfr, acc[ct], 0, 0, 0);
            }
        }
    }
    if (node < N) {
        #pragma unroll
        for (int ct = 0; ct < 8; ++ct) {
            int ch0 = (ct << 4) + (lg << 2);
            float4 bb = *(const float4*)(cb + ch0);
            float4 o;
            o.x = acc[ct][0] + bb.x;
            o.y = acc[ct][1] + bb.y;
            o.z = acc[ct][2] + bb.z;
            o.w = acc[ct][3] + bb.w;
            *(float4*)(out + (size_t)node * 128 + ch0) = o;
        }
    }
}

extern "C" void kernel_launch(void* const* d_in, const int* in_sizes, int n_in,
                              void* d_out, int out_size, void* d_ws, size_t ws_size,
                              hipStream_t stream)
{
    (void)n_in; (void)out_size; (void)ws_size;
    const int*   ops    = (const int*)d_in[0];
    const int*   params = (const int*)d_in[1];
    const int*   esrc   = (const int*)d_in[2];
    const int*   edst   = (const int*)d_in[3];
    const float* opT    = (const float*)d_in[4];
    const float* parT   = (const float*)d_in[5];
    const float* ow1    = (const float*)d_in[6];
    const float* ob1    = (const float*)d_in[7];
    const float* ow2    = (const float*)d_in[8];
    const float* ob2    = (const float*)d_in[9];
    const float* convw  = (const float*)d_in[10];
    const float* convb  = (const float*)d_in[11];
    const float* mw1    = (const float*)d_in[12];
    const float* mb1    = (const float*)d_in[13];
    const float* mw2    = (const float*)d_in[14];
    const float* mb2    = (const float*)d_in[15];
    const float* iw1    = (const float*)d_in[16];
    const float* ib1    = (const float*)d_in[17];
    const float* iw2    = (const float*)d_in[18];
    const float* ib2    = (const float*)d_in[19];
    const float* cw     = (const float*)d_in[20];
    const float* cb     = (const float*)d_in[21];

    const int N = in_sizes[0];      // 100000
    const int E = in_sizes[2];      // 1600000
    const int nb = (N + 511) >> ABITS;   // 196 bins per direction
    const size_t NP = (size_t)N * 128;

    // workspace layout (~162 MB)
    ushort* S0   = (ushort*)d_ws;                    // [N][128] bf16
    ushort* S1   = S0 + NP;
    ushort* S2   = S1 + NP;
    ushort* S3   = S2 + NP;
    ushort* Wt   = S3 + NP;                          // 6 * 16384 bf16 images
    float*  Atab = (float*)(Wt + 6 * 16384);         // 320*128 fp32
    float*  convsum = Atab + 320 * 128;              // 3 layers x 8 replicas x 128
    int*    gcur = (int*)(convsum + 3072);           // 2*nb used, 512 reserved
    uint2*  binbuf = (uint2*)(gcur + 512);           // 2*nb*CAPB entries
    int*    csr_f = (int*)(binbuf + (size_t)2 * nb * CAPB);   // nb*CAPB
    int*    csr_i = csr_f + (size_t)nb * CAPB;
    int*    off_f = csr_i + (size_t)nb * CAPB;       // N each
    int*    cnt_f = off_f + N;
    int*    off_i = cnt_f + N;
    int*    cnt_i = off_i + N;

    float* out1 = (float*)d_out;
    float* out2 = out1 + 128;

    hipMemsetAsync(convsum, 0, sizeof(float) * 3584, stream);   // convsum replicas + gcur

    const int nChunks = (E + CHUNK - 1) / CHUNK;     // 782
    buildprep_kernel<<<nChunks + 160 + 384, 256, 0, stream>>>(
        esrc, edst, E, nb, nChunks, gcur, binbuf,
        opT, parT, ow1, Atab, convw, ow2, cw, Wt);

    const int grid = (N + 127) / 128;                // 782
    mid_kernel<<<2 * nb + grid, 512, 0, stream>>>(
        binbuf, gcur, nb, N,
        csr_f, off_f, cnt_f, csr_i, off_i, cnt_i,
        ops, params, Atab, ob1, Wt + 3 * 16384, ob2, S0);

    const int nBlkF = (N + 15) / 16;                 // 6250
    // layer 0: fwd S0->S1 (colsum rep 0), inv S0->S3   [layer-0 dedup: both read S0]
    glayer_kernel<<<2 * nBlkF, 256, 0, stream>>>(S0, S0, S1, S3,
        csr_f, off_f, cnt_f, csr_i, off_i, cnt_i,
        Wt,             convb,       convsum,        nBlkF, N);
    // layer 1: fwd S1->S0, inv S3->S2
    glayer_kernel<<<2 * nBlkF, 256, 0, stream>>>(S1, S3, S0, S2,
        csr_f, off_f, cnt_f, csr_i, off_i, cnt_i,
        Wt + 16384,     convb + 128, convsum + 1024, nBlkF, N);
    // layer 2: fwd S0->S1, inv S2->S3
    glayer_kernel<<<2 * nBlkF, 256, 0, stream>>>(S0, S2, S1, S3,
        csr_f, off_f, cnt_f, csr_i, off_i, cnt_i,
        Wt + 2 * 16384, convb + 256, convsum + 2048, nBlkF, N);

    // out2 (782 gemm blocks) + final head (1 extra block, overlapped)
    out2_fused<<<grid + 1, 512, 0, stream>>>(S1, S3, Wt + 4 * 16384, cb, out2, grid, N,
                                             convsum, mw1, mb1, mw2, mb2,
                                             iw1, ib1, iw2, ib2, cw, out1);
}